// Round 7
// baseline (195.919 us; speedup 1.0000x reference)
//
#include <hip/hip_runtime.h>
#include <math.h>

// PartTripletLoss on MI355X.
// feature [64,512,256] f32, labels structured (class = j/16, 16 per class),
// margin 0.2, num_pos = 16. Outputs: [loss_mean.mean(), nonzero_num.mean()].
//
// R7: occupancy attack. R6 was 45% idle with grid 512 = 2 blocks/CU hard cap.
//  (a) j-split: grid (NP, 8, 2); each half hinges 4 j-tiles; BOTH halves
//      compute the diagonal Gram (needed for the positive sort) -> 1024
//      blocks, 3 resident/CU, 12 waves/CU (+50%).
//  (b) A-fragments in VGPRs (32 regs, one-time global load) -> no As LDS
//      buffer; LDS 76.5 -> ~27 KB; afrag ds_reads eliminated.
//  (c) __launch_bounds__(256,3) caps VGPR at ~170 for 3 waves/SIMD.
// Kept: sorted-positives hinge (R5), bf16 MFMA 16x16x32 (R4, absmax 0.0),
// XOR-swizzled B tiles (R2), XCD co-location p%8 (R6, FETCH 131->17 MB).

#define MARGIN 0.2f
constexpr int NP = 64;   // parts
constexpr int M = 512;   // samples per part
constexpr int D = 256;   // feature dim
constexpr int SDS = 20;  // sortd/sumt row stride (floats)

typedef __attribute__((ext_vector_type(8))) short bf16x8;
typedef __attribute__((ext_vector_type(4))) float f32x4;

__device__ __forceinline__ unsigned f2bf(float x) {  // fp32 -> bf16 RNE bits
  unsigned b = __float_as_uint(x);
  return (b + 0x7FFFu + ((b >> 16) & 1u)) >> 16;
}
__device__ __forceinline__ uint4 pack8u(float4 v0, float4 v1) {
  uint4 p;
  p.x = f2bf(v0.x) | (f2bf(v0.y) << 16);
  p.y = f2bf(v0.z) | (f2bf(v0.w) << 16);
  p.z = f2bf(v1.x) | (f2bf(v1.y) << 16);
  p.w = f2bf(v1.z) | (f2bf(v1.w) << 16);
  return p;
}
__device__ __forceinline__ bf16x8 pack8b(float4 v0, float4 v1) {
  union { uint4 u; bf16x8 b; } cv;
  cv.u = pack8u(v0, v1);
  return cv.b;
}
__device__ __forceinline__ float sq8(float4 v0, float4 v1) {
  return v0.x * v0.x + v0.y * v0.y + v0.z * v0.z + v0.w * v0.w +
         v1.x * v1.x + v1.y * v1.y + v1.z * v1.z + v1.w * v1.w;
}

__global__ __launch_bounds__(256, 3) void triplet_kernel(
    const float* __restrict__ feat, float* __restrict__ psum,
    float* __restrict__ pcnt) {
  __shared__ unsigned short Bs[64 * 16 * 8];  // 16 KB swizzled bf16 j-tile
  __shared__ float sortd[64 * SDS];           // hp -> sorted asc (5 KB)
  __shared__ float sumt[64 * SDS];            // suffix sums (5 KB)
  __shared__ float x2s[64];                   // current tile row norms
  __shared__ float reds[4], redc[4];

  const int p = blockIdx.x;     // part (lin id % 8 = XCD co-location)
  const int diag = blockIdx.y;  // anchor tile == diagonal j-tile
  const int h = blockIdx.z;     // j-ring half
  const int i0 = diag * 64;
  const int t = threadIdx.x;
  const int w = t >> 6, L = t & 63;
  const int tx = L & 15, quad = L >> 4;
  const int br = t >> 4, bc = t & 15;  // B-staging geometry

  const float* fp = feat + (size_t)p * M * D;

  // ---- A fragments straight to VGPRs (rows i0 + w*16 + tx, K=256) ----
  bf16x8 af[8];
#pragma unroll
  for (int kc = 0; kc < 2; kc++)
#pragma unroll
    for (int ks = 0; ks < 4; ks++) {
      const float* src =
          fp + (size_t)(i0 + w * 16 + tx) * D + kc * 128 + (ks * 4 + quad) * 8;
      af[kc * 4 + ks] = pack8b(((const float4*)src)[0], ((const float4*)src)[1]);
    }

  float x2i[4];
  f32x4 srt[4][4];
  float hsum = 0.f;
  int hcnt = 0;

  // tiles: ti=0 -> tt=0 (diag, both halves, for the sort);
  // h=0 hinges tt {0,1,2,3}; h=1 grams tt0 then hinges tt {4,5,6,7}.
  const int ntiles = 4 + h;
  for (int ti = 0; ti < ntiles; ti++) {
    const int tt = (ti == 0) ? 0 : ti + h * 3;
    const int j0 = ((diag + tt) & 7) * 64;
    f32x4 acc[4];
#pragma unroll
    for (int f = 0; f < 4; f++) acc[f] = (f32x4){0.f, 0.f, 0.f, 0.f};
    float rowss[4];

#pragma unroll
    for (int kc = 0; kc < 2; kc++) {
      __syncthreads();  // prior readers of Bs/x2s done
#pragma unroll
      for (int r4 = 0; r4 < 4; r4++) {
        const int row = br + r4 * 16;
        const float* src = fp + (size_t)(j0 + row) * D + kc * 128 + bc * 8;
        float4 v0 = ((const float4*)src)[0], v1 = ((const float4*)src)[1];
        *(uint4*)&Bs[(row * 16 + (bc ^ (row & 7))) * 8] = pack8u(v0, v1);
        const float s8 = sq8(v0, v1);
        rowss[r4] = kc ? rowss[r4] + s8 : s8;
      }
      if (kc == 1) {  // finish row norms for this j-tile
#pragma unroll
        for (int r4 = 0; r4 < 4; r4++) {
          float ss = rowss[r4];
          ss += __shfl_xor(ss, 8, 16);
          ss += __shfl_xor(ss, 4, 16);
          ss += __shfl_xor(ss, 2, 16);
          ss += __shfl_xor(ss, 1, 16);
          if (bc == 0) x2s[br + r4 * 16] = ss;
        }
      }
      __syncthreads();
#pragma unroll
      for (int ks = 0; ks < 4; ks++) {
        const bf16x8 a = af[kc * 4 + ks];
#pragma unroll
        for (int f = 0; f < 4; f++) {
          const int rowb = f * 16 + tx, cb = ks * 4 + quad;
          bf16x8 b = *(bf16x8*)&Bs[(rowb * 16 + (cb ^ (rowb & 7))) * 8];
          acc[f] =
              __builtin_amdgcn_mfma_f32_16x16x32_bf16(a, b, acc[f], 0, 0, 0);
        }
      }
    }

    // C layout (m89): lane holds col = tx, rows = quad*4 + r.
    if (ti == 0) {  // diagonal: harvest positives, sort, suffix sums
#pragma unroll
      for (int r = 0; r < 4; r++) x2i[r] = x2s[w * 16 + quad * 4 + r];
      const float xj = x2s[w * 16 + tx];
#pragma unroll
      for (int r = 0; r < 4; r++) {
        float d2 = x2i[r] + xj - 2.f * acc[w][r];
        sortd[(w * 16 + quad * 4 + r) * SDS + tx] =
            MARGIN + sqrtf(fmaxf(d2, 0.f));
      }
      __syncthreads();
      if (t < 64) {  // per anchor row: bitonic sort 16 + suffix sums
        float v[16];
#pragma unroll
        for (int q4 = 0; q4 < 4; q4++) {
          f32x4 vv = *(f32x4*)&sortd[t * SDS + q4 * 4];
          v[q4 * 4 + 0] = vv.x; v[q4 * 4 + 1] = vv.y;
          v[q4 * 4 + 2] = vv.z; v[q4 * 4 + 3] = vv.w;
        }
#pragma unroll
        for (int k = 2; k <= 16; k <<= 1)
#pragma unroll
          for (int j = k >> 1; j > 0; j >>= 1)
#pragma unroll
            for (int i = 0; i < 16; i++) {
              const int l = i ^ j;
              if (l > i) {
                const bool asc = ((i & k) == 0);
                if (asc ? (v[i] > v[l]) : (v[i] < v[l])) {
                  float tmp = v[i]; v[i] = v[l]; v[l] = tmp;
                }
              }
            }
#pragma unroll
        for (int q4 = 0; q4 < 4; q4++)
          *(f32x4*)&sortd[t * SDS + q4 * 4] =
              (f32x4){v[q4 * 4], v[q4 * 4 + 1], v[q4 * 4 + 2], v[q4 * 4 + 3]};
        float run = 0.f;
        sumt[t * SDS + 0] = 0.f;
#pragma unroll
        for (int c = 1; c <= 16; c++) {
          run += v[16 - c];
          sumt[t * SDS + c] = run;
        }
      }
      __syncthreads();
#pragma unroll
      for (int r = 0; r < 4; r++)
#pragma unroll
        for (int q4 = 0; q4 < 4; q4++)
          srt[r][q4] = *(f32x4*)&sortd[(w * 16 + quad * 4 + r) * SDS + q4 * 4];

      if (h == 0) {  // hinge the diagonal tile's negative frags
#pragma unroll
        for (int f = 0; f < 4; f++) {
          if (f == w) continue;  // positive block
          const float xj2 = x2s[f * 16 + tx];
#pragma unroll
          for (int r = 0; r < 4; r++) {
            const float dn = sqrtf(fmaxf(x2i[r] + xj2 - 2.f * acc[f][r], 0.f));
            int c = 0;
#define CMP(sv) c += ((sv) > dn) ? 1 : 0;
            CMP(srt[r][0].x) CMP(srt[r][0].y) CMP(srt[r][0].z) CMP(srt[r][0].w)
            CMP(srt[r][1].x) CMP(srt[r][1].y) CMP(srt[r][1].z) CMP(srt[r][1].w)
            CMP(srt[r][2].x) CMP(srt[r][2].y) CMP(srt[r][2].z) CMP(srt[r][2].w)
            CMP(srt[r][3].x) CMP(srt[r][3].y) CMP(srt[r][3].z) CMP(srt[r][3].w)
#undef CMP
            hsum += sumt[(w * 16 + quad * 4 + r) * SDS + c];
            hsum = fmaf(-(float)c, dn, hsum);
            hcnt += c;
          }
        }
      }
    } else {  // off-diagonal: all 16 frags are negatives
#pragma unroll
      for (int f = 0; f < 4; f++) {
        const float xj = x2s[f * 16 + tx];
#pragma unroll
        for (int r = 0; r < 4; r++) {
          const float dn = sqrtf(fmaxf(x2i[r] + xj - 2.f * acc[f][r], 0.f));
          int c = 0;
#define CMP(sv) c += ((sv) > dn) ? 1 : 0;
          CMP(srt[r][0].x) CMP(srt[r][0].y) CMP(srt[r][0].z) CMP(srt[r][0].w)
          CMP(srt[r][1].x) CMP(srt[r][1].y) CMP(srt[r][1].z) CMP(srt[r][1].w)
          CMP(srt[r][2].x) CMP(srt[r][2].y) CMP(srt[r][2].z) CMP(srt[r][2].w)
          CMP(srt[r][3].x) CMP(srt[r][3].y) CMP(srt[r][3].z) CMP(srt[r][3].w)
#undef CMP
          hsum += sumt[(w * 16 + quad * 4 + r) * SDS + c];
          hsum = fmaf(-(float)c, dn, hsum);
          hcnt += c;
        }
      }
    }
  }

  // block reduction
  float cf = (float)hcnt;  // <= 1024 per thread, exact
  for (int off = 32; off > 0; off >>= 1) {
    hsum += __shfl_down(hsum, off, 64);
    cf += __shfl_down(cf, off, 64);
  }
  if (L == 0) { reds[w] = hsum; redc[w] = cf; }
  __syncthreads();
  if (t == 0) {
    psum[p * 16 + diag * 2 + h] = reds[0] + reds[1] + reds[2] + reds[3];
    pcnt[p * 16 + diag * 2 + h] = redc[0] + redc[1] + redc[2] + redc[3];
  }
}

__global__ __launch_bounds__(64) void finalize_kernel(
    const float* __restrict__ psum, const float* __restrict__ pcnt,
    float* __restrict__ out) {
  const int p = threadIdx.x;
  float s = 0.f, c = 0.f;
#pragma unroll
  for (int i = 0; i < 16; i++) {
    s += psum[p * 16 + i];
    c += pcnt[p * 16 + i];
  }
  float lm = (c == 0.f) ? 0.f : s / fmaxf(c, 1.f);
  float ctot = c;
  for (int off = 32; off > 0; off >>= 1) {
    lm += __shfl_down(lm, off, 64);
    ctot += __shfl_down(ctot, off, 64);
  }
  if (p == 0) {
    out[0] = lm / 64.f;
    out[1] = ctot / 64.f;
  }
}

extern "C" void kernel_launch(void* const* d_in, const int* in_sizes, int n_in,
                              void* d_out, int out_size, void* d_ws,
                              size_t ws_size, hipStream_t stream) {
  const float* feat = (const float*)d_in[0];
  float* ws = (float*)d_ws;
  float* psum = ws;         // 1024 floats
  float* pcnt = ws + 1024;  // 1024 floats
  float* out = (float*)d_out;

  dim3 grid(NP, 8, 2);  // lin id % 8 == p % 8 -> part co-located on one XCD
  triplet_kernel<<<grid, 256, 0, stream>>>(feat, psum, pcnt);
  finalize_kernel<<<1, 64, 0, stream>>>(psum, pcnt, out);
}

// Round 8
// 131.591 us; speedup vs baseline: 1.4889x; 1.4889x over previous
//
#include <hip/hip_runtime.h>
#include <math.h>

// PartTripletLoss on MI355X.
// feature [64,512,256] f32, labels structured (class = j/16, 16 per class),
// margin 0.2, num_pos = 16. Outputs: [loss_mean.mean(), nonzero_num.mean()].
//
// R8: R7's ONLY failure was __launch_bounds__(256,3): backend over-achieved
// occupancy (VGPR 84 = 512/6) by spilling af[]/srt[] to scratch -> 55 MB
// scratch writes (WRITE_SIZE counter) + re-reads = the 2x regression.
// Change to (256,2): VGPR cap 256, demand ~130-150 -> no spill; if alloc
// lands <=170 HW still fits 3 waves/EU (the R7 occupancy goal) since LDS
// is only 27 KB. Structure kept from R7:
//  - j-split grid (NP, 8, 2): 1024 blocks, halves hinge 4+4 j-tiles, both
//    compute diagonal Gram for the positive sort.
//  - A-fragments in VGPRs (no As LDS buffer).
//  - sorted-positives hinge (R5), bf16 MFMA 16x16x32 (R4, absmax 0.0),
//    XOR-swizzled B tiles (R2), XCD co-location p%8 (R6: FETCH 131->17 MB).

#define MARGIN 0.2f
constexpr int NP = 64;   // parts
constexpr int M = 512;   // samples per part
constexpr int D = 256;   // feature dim
constexpr int SDS = 20;  // sortd/sumt row stride (floats)

typedef __attribute__((ext_vector_type(8))) short bf16x8;
typedef __attribute__((ext_vector_type(4))) float f32x4;

__device__ __forceinline__ unsigned f2bf(float x) {  // fp32 -> bf16 RNE bits
  unsigned b = __float_as_uint(x);
  return (b + 0x7FFFu + ((b >> 16) & 1u)) >> 16;
}
__device__ __forceinline__ uint4 pack8u(float4 v0, float4 v1) {
  uint4 p;
  p.x = f2bf(v0.x) | (f2bf(v0.y) << 16);
  p.y = f2bf(v0.z) | (f2bf(v0.w) << 16);
  p.z = f2bf(v1.x) | (f2bf(v1.y) << 16);
  p.w = f2bf(v1.z) | (f2bf(v1.w) << 16);
  return p;
}
__device__ __forceinline__ bf16x8 pack8b(float4 v0, float4 v1) {
  union { uint4 u; bf16x8 b; } cv;
  cv.u = pack8u(v0, v1);
  return cv.b;
}
__device__ __forceinline__ float sq8(float4 v0, float4 v1) {
  return v0.x * v0.x + v0.y * v0.y + v0.z * v0.z + v0.w * v0.w +
         v1.x * v1.x + v1.y * v1.y + v1.z * v1.z + v1.w * v1.w;
}

__global__ __launch_bounds__(256, 2) void triplet_kernel(
    const float* __restrict__ feat, float* __restrict__ psum,
    float* __restrict__ pcnt) {
  __shared__ unsigned short Bs[64 * 16 * 8];  // 16 KB swizzled bf16 j-tile
  __shared__ float sortd[64 * SDS];           // hp -> sorted asc (5 KB)
  __shared__ float sumt[64 * SDS];            // suffix sums (5 KB)
  __shared__ float x2s[64];                   // current tile row norms
  __shared__ float reds[4], redc[4];

  const int p = blockIdx.x;     // part (lin id % 8 = XCD co-location)
  const int diag = blockIdx.y;  // anchor tile == diagonal j-tile
  const int h = blockIdx.z;     // j-ring half
  const int i0 = diag * 64;
  const int t = threadIdx.x;
  const int w = t >> 6, L = t & 63;
  const int tx = L & 15, quad = L >> 4;
  const int br = t >> 4, bc = t & 15;  // B-staging geometry

  const float* fp = feat + (size_t)p * M * D;

  // ---- A fragments straight to VGPRs (rows i0 + w*16 + tx, K=256) ----
  bf16x8 af[8];
#pragma unroll
  for (int kc = 0; kc < 2; kc++)
#pragma unroll
    for (int ks = 0; ks < 4; ks++) {
      const float* src =
          fp + (size_t)(i0 + w * 16 + tx) * D + kc * 128 + (ks * 4 + quad) * 8;
      af[kc * 4 + ks] = pack8b(((const float4*)src)[0], ((const float4*)src)[1]);
    }

  float x2i[4];
  f32x4 srt[4][4];
  float hsum = 0.f;
  int hcnt = 0;

  // tiles: ti=0 -> tt=0 (diag, both halves, for the sort);
  // h=0 hinges tt {0,1,2,3}; h=1 grams tt0 then hinges tt {4,5,6,7}.
  const int ntiles = 4 + h;
  for (int ti = 0; ti < ntiles; ti++) {
    const int tt = (ti == 0) ? 0 : ti + h * 3;
    const int j0 = ((diag + tt) & 7) * 64;
    f32x4 acc[4];
#pragma unroll
    for (int f = 0; f < 4; f++) acc[f] = (f32x4){0.f, 0.f, 0.f, 0.f};
    float rowss[4];

#pragma unroll
    for (int kc = 0; kc < 2; kc++) {
      __syncthreads();  // prior readers of Bs/x2s done
#pragma unroll
      for (int r4 = 0; r4 < 4; r4++) {
        const int row = br + r4 * 16;
        const float* src = fp + (size_t)(j0 + row) * D + kc * 128 + bc * 8;
        float4 v0 = ((const float4*)src)[0], v1 = ((const float4*)src)[1];
        *(uint4*)&Bs[(row * 16 + (bc ^ (row & 7))) * 8] = pack8u(v0, v1);
        const float s8 = sq8(v0, v1);
        rowss[r4] = kc ? rowss[r4] + s8 : s8;
      }
      if (kc == 1) {  // finish row norms for this j-tile
#pragma unroll
        for (int r4 = 0; r4 < 4; r4++) {
          float ss = rowss[r4];
          ss += __shfl_xor(ss, 8, 16);
          ss += __shfl_xor(ss, 4, 16);
          ss += __shfl_xor(ss, 2, 16);
          ss += __shfl_xor(ss, 1, 16);
          if (bc == 0) x2s[br + r4 * 16] = ss;
        }
      }
      __syncthreads();
#pragma unroll
      for (int ks = 0; ks < 4; ks++) {
        const bf16x8 a = af[kc * 4 + ks];
#pragma unroll
        for (int f = 0; f < 4; f++) {
          const int rowb = f * 16 + tx, cb = ks * 4 + quad;
          bf16x8 b = *(bf16x8*)&Bs[(rowb * 16 + (cb ^ (rowb & 7))) * 8];
          acc[f] =
              __builtin_amdgcn_mfma_f32_16x16x32_bf16(a, b, acc[f], 0, 0, 0);
        }
      }
    }

    // C layout (m89): lane holds col = tx, rows = quad*4 + r.
    if (ti == 0) {  // diagonal: harvest positives, sort, suffix sums
#pragma unroll
      for (int r = 0; r < 4; r++) x2i[r] = x2s[w * 16 + quad * 4 + r];
      const float xj = x2s[w * 16 + tx];
#pragma unroll
      for (int r = 0; r < 4; r++) {
        float d2 = x2i[r] + xj - 2.f * acc[w][r];
        sortd[(w * 16 + quad * 4 + r) * SDS + tx] =
            MARGIN + sqrtf(fmaxf(d2, 0.f));
      }
      __syncthreads();
      if (t < 64) {  // per anchor row: bitonic sort 16 + suffix sums
        float v[16];
#pragma unroll
        for (int q4 = 0; q4 < 4; q4++) {
          f32x4 vv = *(f32x4*)&sortd[t * SDS + q4 * 4];
          v[q4 * 4 + 0] = vv.x; v[q4 * 4 + 1] = vv.y;
          v[q4 * 4 + 2] = vv.z; v[q4 * 4 + 3] = vv.w;
        }
#pragma unroll
        for (int k = 2; k <= 16; k <<= 1)
#pragma unroll
          for (int j = k >> 1; j > 0; j >>= 1)
#pragma unroll
            for (int i = 0; i < 16; i++) {
              const int l = i ^ j;
              if (l > i) {
                const bool asc = ((i & k) == 0);
                if (asc ? (v[i] > v[l]) : (v[i] < v[l])) {
                  float tmp = v[i]; v[i] = v[l]; v[l] = tmp;
                }
              }
            }
#pragma unroll
        for (int q4 = 0; q4 < 4; q4++)
          *(f32x4*)&sortd[t * SDS + q4 * 4] =
              (f32x4){v[q4 * 4], v[q4 * 4 + 1], v[q4 * 4 + 2], v[q4 * 4 + 3]};
        float run = 0.f;
        sumt[t * SDS + 0] = 0.f;
#pragma unroll
        for (int c = 1; c <= 16; c++) {
          run += v[16 - c];
          sumt[t * SDS + c] = run;
        }
      }
      __syncthreads();
#pragma unroll
      for (int r = 0; r < 4; r++)
#pragma unroll
        for (int q4 = 0; q4 < 4; q4++)
          srt[r][q4] = *(f32x4*)&sortd[(w * 16 + quad * 4 + r) * SDS + q4 * 4];

      if (h == 0) {  // hinge the diagonal tile's negative frags
#pragma unroll
        for (int f = 0; f < 4; f++) {
          if (f == w) continue;  // positive block
          const float xj2 = x2s[f * 16 + tx];
#pragma unroll
          for (int r = 0; r < 4; r++) {
            const float dn = sqrtf(fmaxf(x2i[r] + xj2 - 2.f * acc[f][r], 0.f));
            int c = 0;
#define CMP(sv) c += ((sv) > dn) ? 1 : 0;
            CMP(srt[r][0].x) CMP(srt[r][0].y) CMP(srt[r][0].z) CMP(srt[r][0].w)
            CMP(srt[r][1].x) CMP(srt[r][1].y) CMP(srt[r][1].z) CMP(srt[r][1].w)
            CMP(srt[r][2].x) CMP(srt[r][2].y) CMP(srt[r][2].z) CMP(srt[r][2].w)
            CMP(srt[r][3].x) CMP(srt[r][3].y) CMP(srt[r][3].z) CMP(srt[r][3].w)
#undef CMP
            hsum += sumt[(w * 16 + quad * 4 + r) * SDS + c];
            hsum = fmaf(-(float)c, dn, hsum);
            hcnt += c;
          }
        }
      }
    } else {  // off-diagonal: all 16 frags are negatives
#pragma unroll
      for (int f = 0; f < 4; f++) {
        const float xj = x2s[f * 16 + tx];
#pragma unroll
        for (int r = 0; r < 4; r++) {
          const float dn = sqrtf(fmaxf(x2i[r] + xj - 2.f * acc[f][r], 0.f));
          int c = 0;
#define CMP(sv) c += ((sv) > dn) ? 1 : 0;
          CMP(srt[r][0].x) CMP(srt[r][0].y) CMP(srt[r][0].z) CMP(srt[r][0].w)
          CMP(srt[r][1].x) CMP(srt[r][1].y) CMP(srt[r][1].z) CMP(srt[r][1].w)
          CMP(srt[r][2].x) CMP(srt[r][2].y) CMP(srt[r][2].z) CMP(srt[r][2].w)
          CMP(srt[r][3].x) CMP(srt[r][3].y) CMP(srt[r][3].z) CMP(srt[r][3].w)
#undef CMP
          hsum += sumt[(w * 16 + quad * 4 + r) * SDS + c];
          hsum = fmaf(-(float)c, dn, hsum);
          hcnt += c;
        }
      }
    }
  }

  // block reduction
  float cf = (float)hcnt;  // <= 1024 per thread, exact
  for (int off = 32; off > 0; off >>= 1) {
    hsum += __shfl_down(hsum, off, 64);
    cf += __shfl_down(cf, off, 64);
  }
  if (L == 0) { reds[w] = hsum; redc[w] = cf; }
  __syncthreads();
  if (t == 0) {
    psum[p * 16 + diag * 2 + h] = reds[0] + reds[1] + reds[2] + reds[3];
    pcnt[p * 16 + diag * 2 + h] = redc[0] + redc[1] + redc[2] + redc[3];
  }
}

__global__ __launch_bounds__(64) void finalize_kernel(
    const float* __restrict__ psum, const float* __restrict__ pcnt,
    float* __restrict__ out) {
  const int p = threadIdx.x;
  float s = 0.f, c = 0.f;
#pragma unroll
  for (int i = 0; i < 16; i++) {
    s += psum[p * 16 + i];
    c += pcnt[p * 16 + i];
  }
  float lm = (c == 0.f) ? 0.f : s / fmaxf(c, 1.f);
  float ctot = c;
  for (int off = 32; off > 0; off >>= 1) {
    lm += __shfl_down(lm, off, 64);
    ctot += __shfl_down(ctot, off, 64);
  }
  if (p == 0) {
    out[0] = lm / 64.f;
    out[1] = ctot / 64.f;
  }
}

extern "C" void kernel_launch(void* const* d_in, const int* in_sizes, int n_in,
                              void* d_out, int out_size, void* d_ws,
                              size_t ws_size, hipStream_t stream) {
  const float* feat = (const float*)d_in[0];
  float* ws = (float*)d_ws;
  float* psum = ws;         // 1024 floats
  float* pcnt = ws + 1024;  // 1024 floats
  float* out = (float*)d_out;

  dim3 grid(NP, 8, 2);  // lin id % 8 == p % 8 -> part co-located on one XCD
  triplet_kernel<<<grid, 256, 0, stream>>>(feat, psum, pcnt);
  finalize_kernel<<<1, 64, 0, stream>>>(psum, pcnt, out);
}

// Round 9
// 123.322 us; speedup vs baseline: 1.5887x; 1.0671x over previous
//
#include <hip/hip_runtime.h>
#include <math.h>

// PartTripletLoss on MI355X.
// feature [64,512,256] f32, labels structured (class = j/16, 16 per class),
// margin 0.2, num_pos = 16. Outputs: [loss_mean.mean(), nonzero_num.mean()].
//
// R9: staging-VALU elimination. R8's VALU issue (84k cyc/SIMD, 51% busy) was
// dominated by per-block f32->bf16 pack8 + sq8 + shuffles, repeated for
// every tile touch. Now:
//  - convert_kernel (one HBM pass): feature -> bf16 in d_ws, PRE-SWIZZLED
//    in the exact LDS tile layout (chunk c of row r at c^(r&7)); exact f32
//    row norms x2g computed once.
//  - triplet staging = __builtin_amdgcn_global_load_lds 16B DMA of the full
//    32 KB K=256 tile (linear copy; swizzle already baked in) -> no VGPR
//    round-trip, no pack, 1 barrier pair per tile (was 2).
//  - A-frags read straight from the bf16 tensor.
// Kept: j-split grid (NP,8,2) (R7), sorted-positives hinge (R5), bf16 MFMA
// 16x16x32 (R4, absmax 0.0), XCD co-location p%8 (R6).
// Requires ws_size >= ~17.2 MB (bf16 tensor 16.78 MB + x2 + partials).

#define MARGIN 0.2f
constexpr int NP = 64;   // parts
constexpr int M = 512;   // samples per part
constexpr int D = 256;   // feature dim
constexpr int SDS = 20;  // sortd/sumt row stride (floats)

typedef __attribute__((ext_vector_type(8))) short bf16x8;
typedef __attribute__((ext_vector_type(4))) float f32x4;
typedef __attribute__((address_space(1))) const unsigned int as1_uint;
typedef __attribute__((address_space(3))) unsigned int as3_uint;

__device__ __forceinline__ unsigned f2bf(float x) {  // fp32 -> bf16 RNE bits
  unsigned b = __float_as_uint(x);
  return (b + 0x7FFFu + ((b >> 16) & 1u)) >> 16;
}
__device__ __forceinline__ uint4 pack8u(float4 v0, float4 v1) {
  uint4 p;
  p.x = f2bf(v0.x) | (f2bf(v0.y) << 16);
  p.y = f2bf(v0.z) | (f2bf(v0.w) << 16);
  p.z = f2bf(v1.x) | (f2bf(v1.y) << 16);
  p.w = f2bf(v1.z) | (f2bf(v1.w) << 16);
  return p;
}
__device__ __forceinline__ float sq8(float4 v0, float4 v1) {
  return v0.x * v0.x + v0.y * v0.y + v0.z * v0.z + v0.w * v0.w +
         v1.x * v1.x + v1.y * v1.y + v1.z * v1.z + v1.w * v1.w;
}

// feature f32 -> swizzled bf16 tensor + exact row norms. 8 rows/block.
__global__ __launch_bounds__(256) void convert_kernel(
    const float* __restrict__ feat, unsigned short* __restrict__ fb,
    float* __restrict__ x2g) {
  const int t = threadIdx.x;
  const int R = blockIdx.x * 8 + (t >> 5);  // global row (p*512 + local)
  const int c = t & 31;                     // 16B chunk within row
  const int r = R & 63;                     // row within 64-row tile
  const float* src = feat + (size_t)R * D + c * 8;
  float4 v0 = ((const float4*)src)[0], v1 = ((const float4*)src)[1];
  *(uint4*)&fb[((size_t)R * 32 + (c ^ (r & 7))) * 8] = pack8u(v0, v1);
  float ss = sq8(v0, v1);
  ss += __shfl_xor(ss, 16, 32);
  ss += __shfl_xor(ss, 8, 32);
  ss += __shfl_xor(ss, 4, 32);
  ss += __shfl_xor(ss, 2, 32);
  ss += __shfl_xor(ss, 1, 32);
  if (c == 0) x2g[R] = ss;
}

__global__ __launch_bounds__(256, 2) void triplet_kernel(
    const unsigned short* __restrict__ fb, const float* __restrict__ x2g,
    float* __restrict__ psum, float* __restrict__ pcnt) {
  __shared__ unsigned short Bs[64 * 32 * 8];  // 32 KB: full K=256 j-tile
  __shared__ float sortd[64 * SDS];           // hp -> sorted asc (5 KB)
  __shared__ float sumt[64 * SDS];            // suffix sums (5 KB)
  __shared__ float x2s[64];
  __shared__ float reds[4], redc[4];

  const int p = blockIdx.x;     // part (lin id % 8 = XCD co-location)
  const int diag = blockIdx.y;  // anchor tile == diagonal j-tile
  const int h = blockIdx.z;     // j-ring half
  const int i0 = diag * 64;
  const int t = threadIdx.x;
  const int w = t >> 6, L = t & 63;
  const int tx = L & 15, quad = L >> 4;
  const int tx7 = tx & 7;

  // ---- A fragments from pre-swizzled bf16 tensor (row i0+w*16+tx) ----
  const size_t Ra = (size_t)p * M + i0 + w * 16 + tx;
  bf16x8 af[8];
#pragma unroll
  for (int kc = 0; kc < 2; kc++)
#pragma unroll
    for (int ks = 0; ks < 4; ks++) {
      const int ca = kc * 16 + ks * 4 + quad;
      af[kc * 4 + ks] = *(const bf16x8*)&fb[(Ra * 32 + (ca ^ tx7)) * 8];
    }

  float x2i[4];
#pragma unroll
  for (int r = 0; r < 4; r++)
    x2i[r] = x2g[(size_t)p * M + i0 + w * 16 + quad * 4 + r];

  f32x4 srt[4][4];
  float hsum = 0.f;
  int hcnt = 0;

  // ti=0 -> tt=0 (diag, both halves, for the sort);
  // h=0 hinges tt {0,1,2,3}; h=1 grams tt0 then hinges tt {4,5,6,7}.
  const int ntiles = 4 + h;
  for (int ti = 0; ti < ntiles; ti++) {
    const int tt = (ti == 0) ? 0 : ti + h * 3;
    const int j0 = ((diag + tt) & 7) * 64;

    __syncthreads();  // prior readers of Bs/x2s done
    {  // DMA the 32 KB tile: linear copy, swizzle pre-baked
      const char* gsrc = (const char*)fb + ((size_t)p * M + j0) * 512;
      char* lbase = (char*)Bs + (t >> 6) * 1024;  // wave-uniform
#pragma unroll
      for (int i = 0; i < 8; i++)
        __builtin_amdgcn_global_load_lds(
            (as1_uint*)(gsrc + i * 4096 + t * 16),
            (as3_uint*)(lbase + i * 4096), 16, 0, 0);
      if (t < 64) x2s[t] = x2g[(size_t)p * M + j0 + t];
    }
    __syncthreads();  // drains vmcnt (DMA + x2s)

    f32x4 acc[4];
#pragma unroll
    for (int f = 0; f < 4; f++) acc[f] = (f32x4){0.f, 0.f, 0.f, 0.f};
#pragma unroll
    for (int kc = 0; kc < 2; kc++)
#pragma unroll
      for (int ks = 0; ks < 4; ks++) {
        const bf16x8 a = af[kc * 4 + ks];
        const int cb = kc * 16 + ks * 4 + quad;
#pragma unroll
        for (int f = 0; f < 4; f++) {
          const int rowb = f * 16 + tx;
          bf16x8 b = *(bf16x8*)&Bs[(rowb * 32 + (cb ^ tx7)) * 8];
          acc[f] =
              __builtin_amdgcn_mfma_f32_16x16x32_bf16(a, b, acc[f], 0, 0, 0);
        }
      }

    // C layout (m89): lane holds col = tx, rows = quad*4 + r.
    if (ti == 0) {  // diagonal: harvest positives, sort, suffix sums
      const float xj = x2s[w * 16 + tx];
#pragma unroll
      for (int r = 0; r < 4; r++) {
        float d2 = x2i[r] + xj - 2.f * acc[w][r];
        sortd[(w * 16 + quad * 4 + r) * SDS + tx] =
            MARGIN + sqrtf(fmaxf(d2, 0.f));
      }
      __syncthreads();
      if (t < 64) {  // per anchor row: bitonic sort 16 + suffix sums
        float v[16];
#pragma unroll
        for (int q4 = 0; q4 < 4; q4++) {
          f32x4 vv = *(f32x4*)&sortd[t * SDS + q4 * 4];
          v[q4 * 4 + 0] = vv.x; v[q4 * 4 + 1] = vv.y;
          v[q4 * 4 + 2] = vv.z; v[q4 * 4 + 3] = vv.w;
        }
#pragma unroll
        for (int k = 2; k <= 16; k <<= 1)
#pragma unroll
          for (int j = k >> 1; j > 0; j >>= 1)
#pragma unroll
            for (int i = 0; i < 16; i++) {
              const int l = i ^ j;
              if (l > i) {
                const bool asc = ((i & k) == 0);
                if (asc ? (v[i] > v[l]) : (v[i] < v[l])) {
                  float tmp = v[i]; v[i] = v[l]; v[l] = tmp;
                }
              }
            }
#pragma unroll
        for (int q4 = 0; q4 < 4; q4++)
          *(f32x4*)&sortd[t * SDS + q4 * 4] =
              (f32x4){v[q4 * 4], v[q4 * 4 + 1], v[q4 * 4 + 2], v[q4 * 4 + 3]};
        float run = 0.f;
        sumt[t * SDS + 0] = 0.f;
#pragma unroll
        for (int c = 1; c <= 16; c++) {
          run += v[16 - c];
          sumt[t * SDS + c] = run;
        }
      }
      __syncthreads();
#pragma unroll
      for (int r = 0; r < 4; r++)
#pragma unroll
        for (int q4 = 0; q4 < 4; q4++)
          srt[r][q4] = *(f32x4*)&sortd[(w * 16 + quad * 4 + r) * SDS + q4 * 4];

      if (h == 0) {  // hinge diagonal tile's negative frags
#pragma unroll
        for (int f = 0; f < 4; f++) {
          if (f == w) continue;  // positive block
          const float xj2 = x2s[f * 16 + tx];
#pragma unroll
          for (int r = 0; r < 4; r++) {
            const float dn = sqrtf(fmaxf(x2i[r] + xj2 - 2.f * acc[f][r], 0.f));
            int c = 0;
#define CMP(sv) c += ((sv) > dn) ? 1 : 0;
            CMP(srt[r][0].x) CMP(srt[r][0].y) CMP(srt[r][0].z) CMP(srt[r][0].w)
            CMP(srt[r][1].x) CMP(srt[r][1].y) CMP(srt[r][1].z) CMP(srt[r][1].w)
            CMP(srt[r][2].x) CMP(srt[r][2].y) CMP(srt[r][2].z) CMP(srt[r][2].w)
            CMP(srt[r][3].x) CMP(srt[r][3].y) CMP(srt[r][3].z) CMP(srt[r][3].w)
#undef CMP
            hsum += sumt[(w * 16 + quad * 4 + r) * SDS + c];
            hsum = fmaf(-(float)c, dn, hsum);
            hcnt += c;
          }
        }
      }
    } else {  // off-diagonal: all 16 frags are negatives
#pragma unroll
      for (int f = 0; f < 4; f++) {
        const float xj = x2s[f * 16 + tx];
#pragma unroll
        for (int r = 0; r < 4; r++) {
          const float dn = sqrtf(fmaxf(x2i[r] + xj - 2.f * acc[f][r], 0.f));
          int c = 0;
#define CMP(sv) c += ((sv) > dn) ? 1 : 0;
          CMP(srt[r][0].x) CMP(srt[r][0].y) CMP(srt[r][0].z) CMP(srt[r][0].w)
          CMP(srt[r][1].x) CMP(srt[r][1].y) CMP(srt[r][1].z) CMP(srt[r][1].w)
          CMP(srt[r][2].x) CMP(srt[r][2].y) CMP(srt[r][2].z) CMP(srt[r][2].w)
          CMP(srt[r][3].x) CMP(srt[r][3].y) CMP(srt[r][3].z) CMP(srt[r][3].w)
#undef CMP
          hsum += sumt[(w * 16 + quad * 4 + r) * SDS + c];
          hsum = fmaf(-(float)c, dn, hsum);
          hcnt += c;
        }
      }
    }
  }

  // block reduction
  float cf = (float)hcnt;  // <= 1280 per thread, exact
  for (int off = 32; off > 0; off >>= 1) {
    hsum += __shfl_down(hsum, off, 64);
    cf += __shfl_down(cf, off, 64);
  }
  if (L == 0) { reds[w] = hsum; redc[w] = cf; }
  __syncthreads();
  if (t == 0) {
    psum[p * 16 + diag * 2 + h] = reds[0] + reds[1] + reds[2] + reds[3];
    pcnt[p * 16 + diag * 2 + h] = redc[0] + redc[1] + redc[2] + redc[3];
  }
}

__global__ __launch_bounds__(64) void finalize_kernel(
    const float* __restrict__ psum, const float* __restrict__ pcnt,
    float* __restrict__ out) {
  const int p = threadIdx.x;
  float s = 0.f, c = 0.f;
#pragma unroll
  for (int i = 0; i < 16; i++) {
    s += psum[p * 16 + i];
    c += pcnt[p * 16 + i];
  }
  float lm = (c == 0.f) ? 0.f : s / fmaxf(c, 1.f);
  float ctot = c;
  for (int off = 32; off > 0; off >>= 1) {
    lm += __shfl_down(lm, off, 64);
    ctot += __shfl_down(ctot, off, 64);
  }
  if (p == 0) {
    out[0] = lm / 64.f;
    out[1] = ctot / 64.f;
  }
}

extern "C" void kernel_launch(void* const* d_in, const int* in_sizes, int n_in,
                              void* d_out, int out_size, void* d_ws,
                              size_t ws_size, hipStream_t stream) {
  const float* feat = (const float*)d_in[0];
  float* ws = (float*)d_ws;
  float* psum = ws;           // 1024 floats
  float* pcnt = ws + 1024;    // 1024 floats
  float* x2g = ws + 2048;     // 32768 floats
  unsigned short* fb = (unsigned short*)(ws + 2048 + 32768);  // 16.78 MB bf16
  float* out = (float*)d_out;

  convert_kernel<<<(NP * M) / 8, 256, 0, stream>>>(feat, fb, x2g);
  dim3 grid(NP, 8, 2);  // lin id % 8 == p % 8 -> part co-located on one XCD
  triplet_kernel<<<grid, 256, 0, stream>>>(fb, x2g, psum, pcnt);
  finalize_kernel<<<1, 64, 0, stream>>>(psum, pcnt, out);
}